// Round 8
// baseline (630.621 us; speedup 1.0000x reference)
//
#include <hip/hip_runtime.h>
#include <hip/hip_bf16.h>
#include <cstdint>

// ---------------------------------------------------------------------------
// TransformerClassifier: 2x single-head attention (N=4, L=2048, D=1024) +
// mean-pool + linear + sigmoid.
//
// GEMM v6: 2-pass split-A ((Ahi+Alo).Bh^T) on mfma_f32_32x32x16_bf16:
//   - half the MFMA instruction count of 16x16x32 at +15% measured rate
//   - 2 phases per K-tile (was 4), one merged boundary barrier
//   - A-frag: lane holds row (lane&31), k-octet (khalf*2 + (lane>>5));
//     B-frag symmetric on B^T rows; C/D: col=lane&31,
//     row=(reg&3)+8*(reg>>2)+4*(lane>>5)   [verified m74/m101 mapping]
//   LDS layout/swizzle/staging identical to v5 (conflict-free per-beat).
//
// ws layout (216 MB total):
//   [  0MB) Ahi/Alo : X split, later H1 split      (16+16 MB)
//   [ 32MB) Qhi/Qlo : Q split; later H2 fp32       (16+16 MB)
//   [ 64MB) Khi     : K hi                          (16 MB)
//   [ 96MB) Vthi    : V^T hi                        (16 MB)
//   [128MB) Wt      : 6x W^T hi                     (12 MB)
//   [152MB) S/P     : scores fp32 -> P hi/lo in place (64 MB)
// ---------------------------------------------------------------------------

#define DEVFN __device__ __forceinline__

typedef __attribute__((ext_vector_type(8))) short bf16x8;
typedef __attribute__((ext_vector_type(16))) float f32x16;
typedef unsigned short u16;

DEVFN u16 f2bf(float f) {               // round-to-nearest-even bf16 (finite)
    uint32_t x = __float_as_uint(f);
    x += 0x7fffu + ((x >> 16) & 1u);
    return (u16)(x >> 16);
}
DEVFN float bf2f(u16 u) { return __uint_as_float(((uint32_t)u) << 16); }
DEVFN void split2(float v, u16& h, u16& l) {
    h = f2bf(v);
    l = f2bf(v - bf2f(h));              // exact residual
}

DEVFN void gload_lds16(const void* g, void* l) {
    __builtin_amdgcn_global_load_lds(
        (const __attribute__((address_space(1))) void*)g,
        (__attribute__((address_space(3))) void*)l, 16, 0, 0);
}

#define MFMA32 __builtin_amdgcn_mfma_f32_32x32x16_bf16

// ---------------------------------------------------------------------------
// 2-pass split-A GEMM:  C = scale * ((Ahi+Alo) . Bh^T)
//   A : M x K row-major hi/lo (shared lda);  Bh : N x K row-major bf16
// BN = 256 fixed.  Requires M%BM==0, N%256==0, K%32==0, K/32>=2,
// grid (N/256, M/BM, Z), total blocks % 8 == 0.
// EPI: 0 = hi/lo split row-major; 1 = fp32 row-major;
//      2 = V^T hi-only per-batch;  3 = hi-only row-major
// ---------------------------------------------------------------------------
template<int BM, int EPI>
__global__ __launch_bounds__(512, 2) void gemm2(
    const u16* __restrict__ Ahi, const u16* __restrict__ Alo, long long aStride,
    const u16* __restrict__ Bh, long long bStride,
    void* __restrict__ out0, void* __restrict__ out1, long long cStride,
    int M, int N, int K, int lda, int ldb, int ldc, float scale)
{
    constexpr int ASEC  = BM * 64;           // u16 per buffer, A section
    constexpr int BUFSZ = ASEC + 8192;       // + B section (256 rows x 32 u16)
    constexpr int AU    = BM / 64;           // A stage units (4|2)
    constexpr int NU    = AU + 2;            // total stage units (6|4)
    constexpr int MT    = BM / 64;           // 32x32 M-tiles per wave (4|2)

    __shared__ __align__(16) u16 L[2 * BUFSZ];
    const int tid  = threadIdx.x;
    const int wave = tid >> 6, lane = tid & 63;

    // bijective XCD-aware block swizzle (all launches have nwg % 8 == 0)
    const int gx = gridDim.x, gy = gridDim.y;
    const int nwg = gx * gy * gridDim.z;
    int flat = (blockIdx.z * gy + blockIdx.y) * gx + blockIdx.x;
    flat = (flat & 7) * (nwg >> 3) + (flat >> 3);
    const int bx = flat % gx, by = (flat / gx) % gy, bz = flat / (gx * gy);

    const u16* pAhi = Ahi + (size_t)bz * aStride;
    const u16* pAlo = Alo + (size_t)bz * aStride;
    const u16* pBh  = Bh  + (size_t)bz * bStride;
    const int m0 = by * BM, n0 = bx * 256;

    // ---- staging unit setup (pre-swizzled global sources, linear LDS dest)
    const u16* src[NU];
    int dst[NU];
#pragma unroll
    for (int q = 0; q < AU; q++) {           // A: 8 slots/row, chunk = slot^(row&7)
        const int s = q * 512 + tid, row = s >> 3, c = (s & 7) ^ (row & 7);
        src[q] = (c < 4 ? pAhi : pAlo) + (size_t)(m0 + row) * lda + (c & 3) * 8;
        dst[q] = q * 4096 + wave * 512;
    }
#pragma unroll
    for (int q = 0; q < 2; q++) {            // B: 4 slots/row, chunk = slot^((row>>1)&3)
        const int s = q * 512 + tid, row = s >> 2, c = (s & 3) ^ ((row >> 1) & 3);
        src[AU + q] = pBh + (size_t)(n0 + row) * ldb + c * 8;
        dst[AU + q] = ASEC + q * 4096 + wave * 512;
    }

    // ---- fragment geometry (32x32 frags)
    const int fl = lane & 31, kh = lane >> 5;        // row-in-frag, k-octet half
    const int wm = (wave >> 2) * (BM / 2);           // 2M x 4N decomposition
    const int wn = (wave & 3) * 64;

    const int NT = K >> 5;

    // ---- prologue: stage tile 0 into buffer 0
#pragma unroll
    for (int u = 0; u < NU; u++) { gload_lds16(src[u], &L[dst[u]]); src[u] += 32; }
    asm volatile("s_waitcnt vmcnt(0)" ::: "memory");
    __builtin_amdgcn_s_barrier();

    f32x16 acc[MT][2] = {};
    bf16x8 ah[MT], al[MT], bh[2];
    int cOff = 0;

#define STAGE(u) do { gload_lds16(src[u], &L[sOff + dst[u]]); src[u] += 32; } while (0)

    for (int kt = 0; kt < NT; ++kt) {
        const int sOff = cOff ^ BUFSZ;
        const bool pre = (kt + 1) < NT;

        // ================= phase 0: k-half 0 =================
        {
            const int c = kh;                         // chunk 0|1
#pragma unroll
            for (int i = 0; i < MT; i++) {
                const int r = wm + i * 32 + fl;
                const int x = cOff + r * 64 + ((c ^ (r & 7)) << 3);
                ah[i] = *(const bf16x8*)&L[x];
                al[i] = *(const bf16x8*)&L[x ^ 32];
            }
#pragma unroll
            for (int j = 0; j < 2; j++) {
                const int r = wn + j * 32 + fl;
                const int x = cOff + ASEC + r * 32 + ((c ^ ((r >> 1) & 3)) << 3);
                bh[j] = *(const bf16x8*)&L[x];
            }
        }
        if (pre) { STAGE(0); STAGE(1); if constexpr (NU > 4) STAGE(2); }
        __builtin_amdgcn_s_barrier();
        asm volatile("s_waitcnt lgkmcnt(0)" ::: "memory");
        __builtin_amdgcn_sched_barrier(0);
        __builtin_amdgcn_s_setprio(1);
#pragma unroll
        for (int i = 0; i < MT; i++)
#pragma unroll
            for (int j = 0; j < 2; j++)
                acc[i][j] = MFMA32(ah[i], bh[j], acc[i][j], 0, 0, 0);
#pragma unroll
        for (int i = 0; i < MT; i++)
#pragma unroll
            for (int j = 0; j < 2; j++)
                acc[i][j] = MFMA32(al[i], bh[j], acc[i][j], 0, 0, 0);
        __builtin_amdgcn_s_setprio(0);
        __builtin_amdgcn_s_barrier();

        // ================= phase 1: k-half 1 =================
        {
            const int c = 2 + kh;                     // chunk 2|3
#pragma unroll
            for (int i = 0; i < MT; i++) {
                const int r = wm + i * 32 + fl;
                const int x = cOff + r * 64 + ((c ^ (r & 7)) << 3);
                ah[i] = *(const bf16x8*)&L[x];
                al[i] = *(const bf16x8*)&L[x ^ 32];
            }
#pragma unroll
            for (int j = 0; j < 2; j++) {
                const int r = wn + j * 32 + fl;
                const int x = cOff + ASEC + r * 32 + ((c ^ ((r >> 1) & 3)) << 3);
                bh[j] = *(const bf16x8*)&L[x];
            }
        }
        if (pre) { if constexpr (NU > 4) { STAGE(3); STAGE(4); STAGE(5); }
                   else { STAGE(2); STAGE(3); } }
        __builtin_amdgcn_s_barrier();
        asm volatile("s_waitcnt lgkmcnt(0)" ::: "memory");
        __builtin_amdgcn_sched_barrier(0);
        __builtin_amdgcn_s_setprio(1);
#pragma unroll
        for (int i = 0; i < MT; i++)
#pragma unroll
            for (int j = 0; j < 2; j++)
                acc[i][j] = MFMA32(ah[i], bh[j], acc[i][j], 0, 0, 0);
#pragma unroll
        for (int i = 0; i < MT; i++)
#pragma unroll
            for (int j = 0; j < 2; j++)
                acc[i][j] = MFMA32(al[i], bh[j], acc[i][j], 0, 0, 0);
        __builtin_amdgcn_s_setprio(0);

        // ---- K-tile boundary (merged barrier)
        if (pre) asm volatile("s_waitcnt vmcnt(0)" ::: "memory");
        __builtin_amdgcn_sched_barrier(0);
        __builtin_amdgcn_s_barrier();
        cOff = sOff;
    }
#undef STAGE

    // ---- epilogue: 32x32 C/D: col = lane&31, row = (reg&3)+8*(reg>>2)+4*kh
#pragma unroll
    for (int i = 0; i < MT; i++)
#pragma unroll
        for (int j = 0; j < 2; j++)
#pragma unroll
            for (int g = 0; g < 16; g++) {
                const int row = m0 + wm + i * 32 + (g & 3) + 8 * (g >> 2) + 4 * kh;
                const int col = n0 + wn + j * 32 + fl;
                const float v = acc[i][j][g] * scale;
                if constexpr (EPI == 0) {
                    u16 h, l; split2(v, h, l);
                    const size_t off = (size_t)bz * cStride + (size_t)row * ldc + col;
                    ((u16*)out0)[off] = h;
                    ((u16*)out1)[off] = l;
                } else if constexpr (EPI == 1) {
                    ((float*)out0)[(size_t)bz * cStride + (size_t)row * ldc + col] = v;
                } else if constexpr (EPI == 2) {  // V^T hi-only, per-batch
                    const int b = row >> 11, ll = row & 2047;
                    ((u16*)out0)[(size_t)b * (2048 * 1024) + (size_t)col * 2048 + ll] = f2bf(v);
                } else {                          // EPI == 3: hi-only row-major
                    ((u16*)out0)[(size_t)bz * cStride + (size_t)row * ldc + col] = f2bf(v);
                }
            }
}

// ---------------------------------------------------------------------------
__global__ __launch_bounds__(256) void split_f32(
    const float* __restrict__ x, u16* __restrict__ hi, u16* __restrict__ lo)
{
    const size_t i = ((size_t)blockIdx.x * 256 + threadIdx.x) * 4;
    const float4 v = *(const float4*)&x[i];
    ushort4 h, l;
    split2(v.x, h.x, l.x); split2(v.y, h.y, l.y);
    split2(v.z, h.z, l.z); split2(v.w, h.w, l.w);
    *(ushort4*)&hi[i] = h;
    *(ushort4*)&lo[i] = l;
}

// ---------------------------------------------------------------------------
__global__ __launch_bounds__(256) void transpose_hi(
    const float* __restrict__ W, u16* __restrict__ thi)
{
    __shared__ float t[64][65];
    const int tid = threadIdx.x;
    const int r0 = blockIdx.y * 64, c0 = blockIdx.x * 64;
#pragma unroll
    for (int it = 0; it < 16; it++) {
        const int idx = it * 256 + tid, rr = idx >> 6, cc = idx & 63;
        t[rr][cc] = W[(size_t)(r0 + rr) * 1024 + (c0 + cc)];
    }
    __syncthreads();
#pragma unroll
    for (int it = 0; it < 16; it++) {
        const int idx = it * 256 + tid, nn = idx >> 6, kk = idx & 63;
        thi[(size_t)(c0 + nn) * 1024 + (r0 + kk)] = f2bf(t[kk][nn]);
    }
}

// ---------------------------------------------------------------------------
// Row softmax over 2048 fp32 scores, written IN PLACE as P hi/lo bf16
// ---------------------------------------------------------------------------
__global__ __launch_bounds__(256) void softmax_rows(float* __restrict__ S)
{
    const int r   = blockIdx.x;                 // 0..8191 (batch*2048 + l)
    float* row    = S + (size_t)r * 2048;
    const int tid = threadIdx.x;

    const float4 a = *(const float4*)&row[tid * 8];
    const float4 b = *(const float4*)&row[tid * 8 + 4];
    float v[8] = {a.x, a.y, a.z, a.w, b.x, b.y, b.z, b.w};

    float m = v[0];
#pragma unroll
    for (int j = 1; j < 8; j++) m = fmaxf(m, v[j]);
    for (int o = 32; o; o >>= 1) m = fmaxf(m, __shfl_xor(m, o));
    __shared__ float redm[4], reds[4];
    if ((tid & 63) == 0) redm[tid >> 6] = m;
    __syncthreads();
    m = fmaxf(fmaxf(redm[0], redm[1]), fmaxf(redm[2], redm[3]));

    float e[8], s = 0.f;
#pragma unroll
    for (int j = 0; j < 8; j++) { e[j] = __expf(v[j] - m); s += e[j]; }
    for (int o = 32; o; o >>= 1) s += __shfl_xor(s, o);
    if ((tid & 63) == 0) reds[tid >> 6] = s;
    __syncthreads();
    s = reds[0] + reds[1] + reds[2] + reds[3];
    const float inv = 1.f / s;

    u16* ph = (u16*)row;
    u16* pl = ph + 2048;
#pragma unroll
    for (int j = 0; j < 8; j++) {
        u16 h, l; split2(e[j] * inv, h, l);
        ph[tid * 8 + j] = h;
        pl[tid * 8 + j] = l;
    }
}

// ---------------------------------------------------------------------------
__global__ __launch_bounds__(256) void pool_partial(
    const float* __restrict__ H2, const float* __restrict__ wO,
    float* __restrict__ partial)
{
    const int b = blockIdx.x, chunk = blockIdx.y;
    const int tid = threadIdx.x;
    const float* Hb = H2 + (size_t)b * 2048 * 1024 + (size_t)chunk * 64 * 1024;
    const float4 w = *(const float4*)&wO[tid * 4];
    float acc = 0.f;
#pragma unroll 4
    for (int l = 0; l < 64; l++) {
        const float4 h = *(const float4*)&Hb[(size_t)l * 1024 + tid * 4];
        acc += h.x * w.x + h.y * w.y + h.z * w.z + h.w * w.w;
    }
    for (int o = 32; o; o >>= 1) acc += __shfl_xor(acc, o);
    __shared__ float red[4];
    if ((tid & 63) == 0) red[tid >> 6] = acc;
    __syncthreads();
    if (tid == 0) partial[b * 32 + chunk] = red[0] + red[1] + red[2] + red[3];
}

__global__ void head_final(const float* __restrict__ partial,
                           const float* __restrict__ bO, float* __restrict__ out)
{
    const int b = threadIdx.x;                  // 0..3
    if (b >= 4) return;
    float s = 0.f;
#pragma unroll
    for (int c = 0; c < 32; c++) s += partial[b * 32 + c];
    const float logit = s * (1.f / 2048.f) + bO[0];
    out[b] = 1.f / (1.f + __expf(-logit));
}

// ---------------------------------------------------------------------------
extern "C" void kernel_launch(void* const* d_in, const int* in_sizes, int n_in,
                              void* d_out, int out_size, void* d_ws, size_t ws_size,
                              hipStream_t stream)
{
    const float* X   = (const float*)d_in[0];
    const float* Wq1 = (const float*)d_in[1];
    const float* Wk1 = (const float*)d_in[2];
    const float* Wv1 = (const float*)d_in[3];
    const float* Wq2 = (const float*)d_in[4];
    const float* Wk2 = (const float*)d_in[5];
    const float* Wv2 = (const float*)d_in[6];
    const float* WO  = (const float*)d_in[7];
    const float* bO  = (const float*)d_in[8];
    float* out = (float*)d_out;

    uint8_t* ws = (uint8_t*)d_ws;
    const size_t MB = 1ull << 20;
    u16* Ahi  = (u16*)(ws + 0);        u16* Alo  = (u16*)(ws + 16 * MB);
    u16* Qhi  = (u16*)(ws + 32 * MB);  u16* Qlo  = (u16*)(ws + 48 * MB);
    u16* Khi  = (u16*)(ws + 64 * MB);
    u16* Vthi = (u16*)(ws + 96 * MB);
    u16* Wt   = (u16*)(ws + 128 * MB);               // 6 x W^T hi (1M u16 each)
    float* S  = (float*)(ws + 152 * MB);             // 64 MB scores / P
    float* H2 = (float*)(ws + 32 * MB);              // aliases Q (dead by then)
    float* partial = (float*)(ws + 80 * MB);         // free region

    auto Wh = [&](int i) { return Wt + (size_t)i * 1048576; };
    const float* Wsrc[6] = {Wq1, Wk1, Wv1, Wq2, Wk2, Wv2};

    // ---- prep: split X, transpose weights (hi only)
    split_f32<<<8192, 256, 0, stream>>>(X, Ahi, Alo);   // 8M elems
    for (int i = 0; i < 6; i++)
        transpose_hi<<<dim3(16, 16), 256, 0, stream>>>(Wsrc[i], Wh(i));

    const long long LD2 = 2048LL * 1024;   // 2M: Q/K/V & H batch stride
    const long long SST = 2048LL * 2048;   // 4M: S batch stride (floats)
    const long long PST = 2048LL * 4096;   // 8M: P batch stride (u16)

    for (int blk = 0; blk < 2; blk++) {
        const int w0 = blk * 3;
        // projections: BM=128, BN=256 -> grid (4, 64) = 256 blocks
        gemm2<128, 0><<<dim3(4, 64, 1), 512, 0, stream>>>(
            Ahi, Alo, 0, Wh(w0 + 0), 0, Qhi, Qlo, 0,
            8192, 1024, 1024, 1024, 1024, 1024, 1.f);
        gemm2<128, 3><<<dim3(4, 64, 1), 512, 0, stream>>>(
            Ahi, Alo, 0, Wh(w0 + 1), 0, Khi, nullptr, 0,
            8192, 1024, 1024, 1024, 1024, 1024, 1.f);
        gemm2<128, 2><<<dim3(4, 64, 1), 512, 0, stream>>>(
            Ahi, Alo, 0, Wh(w0 + 2), 0, Vthi, nullptr, 0,
            8192, 1024, 1024, 1024, 1024, 1024, 1.f);
        // S = Q.K^T / sqrt(D): BM=256 -> grid (8, 8, 4) = 256 blocks
        gemm2<256, 1><<<dim3(8, 8, 4), 512, 0, stream>>>(
            Qhi, Qlo, LD2, Khi, LD2, S, nullptr, SST,
            2048, 2048, 1024, 1024, 1024, 2048, 0.03125f);
        // softmax rows, in-place -> P hi/lo
        softmax_rows<<<8192, 256, 0, stream>>>(S);
        // O = P.V: BM=128 -> grid (4, 16, 4) = 256 blocks
        if (blk == 0) {
            gemm2<128, 0><<<dim3(4, 16, 4), 512, 0, stream>>>(
                (u16*)S, (u16*)S + 2048, PST, Vthi, LD2, Ahi, Alo, LD2,
                2048, 1024, 2048, 4096, 2048, 1024, 1.f);   // H1 split -> A region
        } else {
            gemm2<128, 1><<<dim3(4, 16, 4), 512, 0, stream>>>(
                (u16*)S, (u16*)S + 2048, PST, Vthi, LD2, H2, nullptr, LD2,
                2048, 1024, 2048, 4096, 2048, 1024, 1.f);   // H2 fp32
        }
    }

    pool_partial<<<dim3(4, 32), 256, 0, stream>>>(H2, WO, partial);
    head_final<<<1, 64, 0, stream>>>(partial, bO, out);
}

// Round 9
// 506.806 us; speedup vs baseline: 1.2443x; 1.2443x over previous
//
#include <hip/hip_runtime.h>
#include <hip/hip_bf16.h>
#include <cstdint>

// ---------------------------------------------------------------------------
// TransformerClassifier: 2x single-head attention (N=4, L=2048, D=1024) +
// mean-pool + linear + sigmoid.
//
// GEMM v7: back to the proven m97-style loop (R3 measured 925 TF-effective,
// 0 bank conflicts): 128x128 tile, BK=32, 256 thr (4 waves, 64x64 each),
// double-buffered LDS, ONE __syncthreads per K-tile, no asm barriers --
// compiler schedules lgkmcnt finely; cross-block TLP (3+ blocks/CU) hides
// the vmcnt drain.
//
// Numerics: PASSES template.
//   2-pass: C = (Ahi+Alo).Bh^T   (Q-proj, QK^T, PV-1 -- softmax-critical)
//   1-pass: C = Ahi.Bh^T         (K/V projections: their outputs are
//           rounded to bf16 anyway so the lo-pass is wasted; PV-2: feeds
//           only the mean-pool head, error ~2e-3 at the sigmoid output)
//
// LDS per buffer: A 128x(64|32) u16 swizzled + B 128x32 u16 swizzled.
// A(2-pass) rows = 8x16B slots (hi 0-3, lo 4-7), slot = chunk^(row&7);
// A(1-pass)/B rows = 4x16B slots, slot = chunk^((row>>1)&3).
// Swizzles realized via pre-swizzled GLOBAL source addrs (rule #21).
//
// ws layout (216 MB):
//   [  0MB) Ahi/Alo : X split, later H1 split      (16+16 MB)
//   [ 32MB) Qhi/Qlo : Q split; later H2 fp32       (16+16 MB)
//   [ 64MB) Khi     : K bf16                        (16 MB)
//   [ 96MB) Vthi    : V^T bf16                      (16 MB)
//   [128MB) Wt      : 6x W^T bf16                   (12 MB)
//   [152MB) S/P     : scores fp32 -> P hi/lo in place (64 MB)
// ---------------------------------------------------------------------------

#define DEVFN __device__ __forceinline__

typedef __attribute__((ext_vector_type(8))) short bf16x8;
typedef __attribute__((ext_vector_type(4))) float f32x4;
typedef unsigned short u16;

DEVFN u16 f2bf(float f) {               // round-to-nearest-even bf16 (finite)
    uint32_t x = __float_as_uint(f);
    x += 0x7fffu + ((x >> 16) & 1u);
    return (u16)(x >> 16);
}
DEVFN float bf2f(u16 u) { return __uint_as_float(((uint32_t)u) << 16); }
DEVFN void split2(float v, u16& h, u16& l) {
    h = f2bf(v);
    l = f2bf(v - bf2f(h));              // exact residual
}

DEVFN void gload_lds16(const void* g, void* l) {
    __builtin_amdgcn_global_load_lds(
        (const __attribute__((address_space(1))) void*)g,
        (__attribute__((address_space(3))) void*)l, 16, 0, 0);
}

#define MFMA16 __builtin_amdgcn_mfma_f32_16x16x32_bf16

// ---------------------------------------------------------------------------
// Split-A GEMM:  C = scale * (A . Bh^T),  A = Ahi (+ Alo if PASSES==2)
//   A : M x K row-major (lda);  Bh : N x K row-major bf16 (ldb)
// Tile 128x128, BK=32.  Requires M%128==0, N%128==0, K%32==0, K/32>=2,
// grid (N/128, M/128, Z), total blocks % 8 == 0.
// EPI: 0 = hi/lo split row-major; 1 = fp32 row-major;
//      2 = V^T bf16 per-batch;    3 = bf16 row-major
// ---------------------------------------------------------------------------
template<int PASSES, int EPI>
__global__ __launch_bounds__(256, 3) void gemmk(
    const u16* __restrict__ Ahi, const u16* __restrict__ Alo, long long aStride,
    const u16* __restrict__ Bh, long long bStride,
    void* __restrict__ out0, void* __restrict__ out1, long long cStride,
    int M, int N, int K, int lda, int ldb, int ldc, float scale)
{
    constexpr int ASEC  = (PASSES == 2) ? 128 * 64 : 128 * 32;  // u16
    constexpr int BUFSZ = ASEC + 128 * 32;
    constexpr int AU    = (PASSES == 2) ? 4 : 2;    // A stage units
    constexpr int NU    = AU + 2;                   // + B units

    __shared__ __align__(16) u16 L[2 * BUFSZ];
    const int tid  = threadIdx.x;
    const int wave = tid >> 6, lane = tid & 63;

    // bijective XCD-aware block swizzle (all launches have nwg % 8 == 0)
    const int gx = gridDim.x, gy = gridDim.y;
    const int nwg = gx * gy * gridDim.z;
    int flat = (blockIdx.z * gy + blockIdx.y) * gx + blockIdx.x;
    flat = (flat & 7) * (nwg >> 3) + (flat >> 3);
    const int bx = flat % gx, by = (flat / gx) % gy, bz = flat / (gx * gy);

    const u16* pAhi = Ahi + (size_t)bz * aStride;
    const u16* pAlo = (PASSES == 2) ? Alo + (size_t)bz * aStride : nullptr;
    const u16* pBh  = Bh + (size_t)bz * bStride;
    const int m0 = by * 128, n0 = bx * 128;

    // ---- staging units: each unit = 2048 u16 (256 thr x 16B), linear dest
    const u16* src[NU];
    int dst[NU];
#pragma unroll
    for (int q = 0; q < AU; q++) {
        const int s = q * 256 + tid;
        if constexpr (PASSES == 2) {     // 8 slots/row, chunk = slot^(row&7)
            const int row = s >> 3, c = (s & 7) ^ (row & 7);
            src[q] = (c < 4 ? pAhi : pAlo) + (size_t)(m0 + row) * lda + (c & 3) * 8;
        } else {                         // 4 slots/row, chunk = slot^((row>>1)&3)
            const int row = s >> 2, c = (s & 3) ^ ((row >> 1) & 3);
            src[q] = pAhi + (size_t)(m0 + row) * lda + c * 8;
        }
        dst[q] = q * 2048 + wave * 512;
    }
#pragma unroll
    for (int q = 0; q < 2; q++) {        // B: 4 slots/row
        const int s = q * 256 + tid, row = s >> 2, c = (s & 3) ^ ((row >> 1) & 3);
        src[AU + q] = pBh + (size_t)(n0 + row) * ldb + c * 8;
        dst[AU + q] = ASEC + q * 2048 + wave * 512;
    }

    // ---- fragment geometry (16x16 frags; wave = 64x64 quadrant)
    const int fr = lane & 15, ch = lane >> 4;
    const int wr = (wave >> 1) * 64, wc = (wave & 1) * 64;

    const int NT = K >> 5;

    // ---- prologue: stage tile 0 into buffer 0
#pragma unroll
    for (int u = 0; u < NU; u++) { gload_lds16(src[u], &L[dst[u]]); src[u] += 32; }
    __syncthreads();

    f32x4 acc[4][4] = {};
    int cur = 0;

    for (int kt = 0; kt < NT; ++kt) {
        const int cOff = cur * BUFSZ;
        const int sOff = BUFSZ - cOff;
        if (kt + 1 < NT) {
#pragma unroll
            for (int u = 0; u < NU; u++) { gload_lds16(src[u], &L[sOff + dst[u]]); src[u] += 32; }
        }

        bf16x8 ah[4], al[4], bh[4];
#pragma unroll
        for (int i = 0; i < 4; i++) {
            const int r = wr + i * 16 + fr;
            if constexpr (PASSES == 2) {
                const int x = cOff + r * 64 + ((ch ^ (r & 7)) << 3);
                ah[i] = *(const bf16x8*)&L[x];
                al[i] = *(const bf16x8*)&L[x ^ 32];
            } else {
                const int x = cOff + r * 32 + ((ch ^ ((r >> 1) & 3)) << 3);
                ah[i] = *(const bf16x8*)&L[x];
            }
        }
#pragma unroll
        for (int j = 0; j < 4; j++) {
            const int r = wc + j * 16 + fr;
            const int x = cOff + ASEC + r * 32 + ((ch ^ ((r >> 1) & 3)) << 3);
            bh[j] = *(const bf16x8*)&L[x];
        }

#pragma unroll
        for (int i = 0; i < 4; i++)
#pragma unroll
            for (int j = 0; j < 4; j++)
                acc[i][j] = MFMA16(ah[i], bh[j], acc[i][j], 0, 0, 0);
        if constexpr (PASSES == 2) {
#pragma unroll
            for (int i = 0; i < 4; i++)
#pragma unroll
                for (int j = 0; j < 4; j++)
                    acc[i][j] = MFMA16(al[i], bh[j], acc[i][j], 0, 0, 0);
        }
        __syncthreads();     // drains vmcnt (staging) + lgkm; swap buffers
        cur ^= 1;
    }

    // ---- epilogue: C/D layout col = lane&15, row = (lane>>4)*4 + r
#pragma unroll
    for (int i = 0; i < 4; i++)
#pragma unroll
        for (int j = 0; j < 4; j++)
#pragma unroll
            for (int r = 0; r < 4; r++) {
                const int row = m0 + wr + i * 16 + (lane >> 4) * 4 + r;
                const int col = n0 + wc + j * 16 + (lane & 15);
                const float v = acc[i][j][r] * scale;
                if constexpr (EPI == 0) {
                    u16 h, l; split2(v, h, l);
                    const size_t off = (size_t)bz * cStride + (size_t)row * ldc + col;
                    ((u16*)out0)[off] = h;
                    ((u16*)out1)[off] = l;
                } else if constexpr (EPI == 1) {
                    ((float*)out0)[(size_t)bz * cStride + (size_t)row * ldc + col] = v;
                } else if constexpr (EPI == 2) {  // V^T bf16, per-batch
                    const int b = row >> 11, ll = row & 2047;
                    ((u16*)out0)[(size_t)b * (2048 * 1024) + (size_t)col * 2048 + ll] = f2bf(v);
                } else {                          // EPI == 3: bf16 row-major
                    ((u16*)out0)[(size_t)bz * cStride + (size_t)row * ldc + col] = f2bf(v);
                }
            }
}

// ---------------------------------------------------------------------------
__global__ __launch_bounds__(256) void split_f32(
    const float* __restrict__ x, u16* __restrict__ hi, u16* __restrict__ lo)
{
    const size_t i = ((size_t)blockIdx.x * 256 + threadIdx.x) * 4;
    const float4 v = *(const float4*)&x[i];
    ushort4 h, l;
    split2(v.x, h.x, l.x); split2(v.y, h.y, l.y);
    split2(v.z, h.z, l.z); split2(v.w, h.w, l.w);
    *(ushort4*)&hi[i] = h;
    *(ushort4*)&lo[i] = l;
}

// ---------------------------------------------------------------------------
__global__ __launch_bounds__(256) void transpose_hi(
    const float* __restrict__ W, u16* __restrict__ thi)
{
    __shared__ float t[64][65];
    const int tid = threadIdx.x;
    const int r0 = blockIdx.y * 64, c0 = blockIdx.x * 64;
#pragma unroll
    for (int it = 0; it < 16; it++) {
        const int idx = it * 256 + tid, rr = idx >> 6, cc = idx & 63;
        t[rr][cc] = W[(size_t)(r0 + rr) * 1024 + (c0 + cc)];
    }
    __syncthreads();
#pragma unroll
    for (int it = 0; it < 16; it++) {
        const int idx = it * 256 + tid, nn = idx >> 6, kk = idx & 63;
        thi[(size_t)(c0 + nn) * 1024 + (r0 + kk)] = f2bf(t[kk][nn]);
    }
}

// ---------------------------------------------------------------------------
// Row softmax over 2048 fp32 scores, written IN PLACE as P hi/lo bf16
// ---------------------------------------------------------------------------
__global__ __launch_bounds__(256) void softmax_rows(float* __restrict__ S)
{
    const int r   = blockIdx.x;                 // 0..8191 (batch*2048 + l)
    float* row    = S + (size_t)r * 2048;
    const int tid = threadIdx.x;

    const float4 a = *(const float4*)&row[tid * 8];
    const float4 b = *(const float4*)&row[tid * 8 + 4];
    float v[8] = {a.x, a.y, a.z, a.w, b.x, b.y, b.z, b.w};

    float m = v[0];
#pragma unroll
    for (int j = 1; j < 8; j++) m = fmaxf(m, v[j]);
    for (int o = 32; o; o >>= 1) m = fmaxf(m, __shfl_xor(m, o));
    __shared__ float redm[4], reds[4];
    if ((tid & 63) == 0) redm[tid >> 6] = m;
    __syncthreads();
    m = fmaxf(fmaxf(redm[0], redm[1]), fmaxf(redm[2], redm[3]));

    float e[8], s = 0.f;
#pragma unroll
    for (int j = 0; j < 8; j++) { e[j] = __expf(v[j] - m); s += e[j]; }
    for (int o = 32; o; o >>= 1) s += __shfl_xor(s, o);
    if ((tid & 63) == 0) reds[tid >> 6] = s;
    __syncthreads();
    s = reds[0] + reds[1] + reds[2] + reds[3];
    const float inv = 1.f / s;

    u16* ph = (u16*)row;
    u16* pl = ph + 2048;
#pragma unroll
    for (int j = 0; j < 8; j++) {
        u16 h, l; split2(e[j] * inv, h, l);
        ph[tid * 8 + j] = h;
        pl[tid * 8 + j] = l;
    }
}

// ---------------------------------------------------------------------------
__global__ __launch_bounds__(256) void pool_partial(
    const float* __restrict__ H2, const float* __restrict__ wO,
    float* __restrict__ partial)
{
    const int b = blockIdx.x, chunk = blockIdx.y;
    const int tid = threadIdx.x;
    const float* Hb = H2 + (size_t)b * 2048 * 1024 + (size_t)chunk * 64 * 1024;
    const float4 w = *(const float4*)&wO[tid * 4];
    float acc = 0.f;
#pragma unroll 4
    for (int l = 0; l < 64; l++) {
        const float4 h = *(const float4*)&Hb[(size_t)l * 1024 + tid * 4];
        acc += h.x * w.x + h.y * w.y + h.z * w.z + h.w * w.w;
    }
    for (int o = 32; o; o >>= 1) acc += __shfl_xor(acc, o);
    __shared__ float red[4];
    if ((tid & 63) == 0) red[tid >> 6] = acc;
    __syncthreads();
    if (tid == 0) partial[b * 32 + chunk] = red[0] + red[1] + red[2] + red[3];
}

__global__ void head_final(const float* __restrict__ partial,
                           const float* __restrict__ bO, float* __restrict__ out)
{
    const int b = threadIdx.x;                  // 0..3
    if (b >= 4) return;
    float s = 0.f;
#pragma unroll
    for (int c = 0; c < 32; c++) s += partial[b * 32 + c];
    const float logit = s * (1.f / 2048.f) + bO[0];
    out[b] = 1.f / (1.f + __expf(-logit));
}

// ---------------------------------------------------------------------------
extern "C" void kernel_launch(void* const* d_in, const int* in_sizes, int n_in,
                              void* d_out, int out_size, void* d_ws, size_t ws_size,
                              hipStream_t stream)
{
    const float* X   = (const float*)d_in[0];
    const float* Wq1 = (const float*)d_in[1];
    const float* Wk1 = (const float*)d_in[2];
    const float* Wv1 = (const float*)d_in[3];
    const float* Wq2 = (const float*)d_in[4];
    const float* Wk2 = (const float*)d_in[5];
    const float* Wv2 = (const float*)d_in[6];
    const float* WO  = (const float*)d_in[7];
    const float* bO  = (const float*)d_in[8];
    float* out = (float*)d_out;

    uint8_t* ws = (uint8_t*)d_ws;
    const size_t MB = 1ull << 20;
    u16* Ahi  = (u16*)(ws + 0);        u16* Alo  = (u16*)(ws + 16 * MB);
    u16* Qhi  = (u16*)(ws + 32 * MB);  u16* Qlo  = (u16*)(ws + 48 * MB);
    u16* Khi  = (u16*)(ws + 64 * MB);
    u16* Vthi = (u16*)(ws + 96 * MB);
    u16* Wt   = (u16*)(ws + 128 * MB);               // 6 x W^T bf16 (1M u16 each)
    float* S  = (float*)(ws + 152 * MB);             // 64 MB scores / P
    float* H2 = (float*)(ws + 32 * MB);              // aliases Q (dead by then)
    float* partial = (float*)(ws + 80 * MB);         // free region

    auto Wh = [&](int i) { return Wt + (size_t)i * 1048576; };
    const float* Wsrc[6] = {Wq1, Wk1, Wv1, Wq2, Wk2, Wv2};

    // ---- prep: split X, transpose weights (bf16)
    split_f32<<<8192, 256, 0, stream>>>(X, Ahi, Alo);   // 8M elems
    for (int i = 0; i < 6; i++)
        transpose_hi<<<dim3(16, 16), 256, 0, stream>>>(Wsrc[i], Wh(i));

    const long long LD2 = 2048LL * 1024;   // 2M: Q/K/V & H batch stride
    const long long SST = 2048LL * 2048;   // 4M: S batch stride (floats)
    const long long PST = 2048LL * 4096;   // 8M: P batch stride (u16)

    for (int blk = 0; blk < 2; blk++) {
        const int w0 = blk * 3;
        // Q proj: 2-pass, hi/lo out.  grid (1024/128=8, 8192/128=64) = 512
        gemmk<2, 0><<<dim3(8, 64, 1), 256, 0, stream>>>(
            Ahi, Alo, 0, Wh(w0 + 0), 0, Qhi, Qlo, 0,
            8192, 1024, 1024, 1024, 1024, 1024, 1.f);
        // K proj: 1-pass (output rounds to bf16 anyway)
        gemmk<1, 3><<<dim3(8, 64, 1), 256, 0, stream>>>(
            Ahi, nullptr, 0, Wh(w0 + 1), 0, Khi, nullptr, 0,
            8192, 1024, 1024, 1024, 1024, 1024, 1.f);
        // V proj: 1-pass, transposed bf16 out
        gemmk<1, 2><<<dim3(8, 64, 1), 256, 0, stream>>>(
            Ahi, nullptr, 0, Wh(w0 + 2), 0, Vthi, nullptr, 0,
            8192, 1024, 1024, 1024, 1024, 1024, 1.f);
        // S = Q.K^T / sqrt(D): 2-pass. grid (16, 16, 4) = 1024
        gemmk<2, 1><<<dim3(16, 16, 4), 256, 0, stream>>>(
            Qhi, Qlo, LD2, Khi, LD2, S, nullptr, SST,
            2048, 2048, 1024, 1024, 1024, 2048, 0.03125f);
        // softmax rows, in-place -> P hi/lo
        softmax_rows<<<8192, 256, 0, stream>>>(S);
        // O = P.V: grid (8, 16, 4) = 512
        if (blk == 0) {
            // PV-1: 2-pass (feeds block-2 softmax path), H1 hi/lo -> A region
            gemmk<2, 0><<<dim3(8, 16, 4), 256, 0, stream>>>(
                (u16*)S, (u16*)S + 2048, PST, Vthi, LD2, Ahi, Alo, LD2,
                2048, 1024, 2048, 4096, 2048, 1024, 1.f);
        } else {
            // PV-2: 1-pass (feeds only mean-pool head), H2 fp32
            gemmk<1, 1><<<dim3(8, 16, 4), 256, 0, stream>>>(
                (u16*)S, nullptr, PST, Vthi, LD2, H2, nullptr, LD2,
                2048, 1024, 2048, 4096, 2048, 1024, 1.f);
        }
    }

    pool_partial<<<dim3(4, 32), 256, 0, stream>>>(H2, WO, partial);
    head_final<<<1, 64, 0, stream>>>(partial, bO, out);
}

// Round 10
// 378.085 us; speedup vs baseline: 1.6679x; 1.3405x over previous
//
#include <hip/hip_runtime.h>
#include <hip/hip_bf16.h>
#include <cstdint>

// ---------------------------------------------------------------------------
// TransformerClassifier: 2x single-head attention (N=4, L=2048, D=1024) +
// mean-pool + linear + sigmoid.
//
// v8: PURE bf16 pipeline (1-pass everywhere) on the proven m97-style GEMM
// (R9: 925 TF-eff, 0 bank conflicts).  R7->R9 showed absmax is insensitive
// to A-side lo-passes (dominated by unavoidable P/K/V bf16 roundings), so
// the remaining lo-passes (Q-proj, QK^T, PV-1; ~130us) are dropped.
//
// GEMM: 128x128 tile, BK=32, 256 thr (4 waves, 64x64 each), double-buffered
// LDS (16KB/buf), ONE __syncthreads per K-tile, global_load_lds staging with
// pre-swizzled global sources (rule #21); A/B rows = 4x16B slots,
// slot = chunk ^ ((row>>1)&3)  (conflict-free, verified R9).
//
// ws layout (216 MB):
//   [  0MB) Xb   : X bf16; overwritten by H1 bf16   (16 MB)
//   [ 16MB) (free)
//   [ 32MB) Qb   : Q bf16; region reused for H2 fp32 (16/32 MB)
//   [ 64MB) Kb   : K bf16                            (16 MB)
//   [ 80MB) partial
//   [ 96MB) Vtb  : V^T bf16 (per-batch [d][l])       (16 MB)
//   [128MB) Wt   : 6x W^T bf16                       (12 MB)
//   [152MB) S/P  : scores fp32 -> P bf16 in place    (64 MB)
// ---------------------------------------------------------------------------

#define DEVFN __device__ __forceinline__

typedef __attribute__((ext_vector_type(8))) short bf16x8;
typedef __attribute__((ext_vector_type(4))) float f32x4;
typedef unsigned short u16;

DEVFN u16 f2bf(float f) {               // round-to-nearest-even bf16 (finite)
    uint32_t x = __float_as_uint(f);
    x += 0x7fffu + ((x >> 16) & 1u);
    return (u16)(x >> 16);
}

DEVFN void gload_lds16(const void* g, void* l) {
    __builtin_amdgcn_global_load_lds(
        (const __attribute__((address_space(1))) void*)g,
        (__attribute__((address_space(3))) void*)l, 16, 0, 0);
}

#define MFMA16 __builtin_amdgcn_mfma_f32_16x16x32_bf16

// ---------------------------------------------------------------------------
// bf16 GEMM:  C = scale * (A . B^T)
//   A : M x K row-major bf16 (lda);  B : N x K row-major bf16 (ldb)
// Tile 128x128, BK=32.  Requires M%128==0, N%128==0, K%32==0, K/32>=2,
// grid (N/128, M/128, Z), total blocks % 8 == 0.
// EPI: 1 = fp32 row-major;  2 = V^T bf16 per-batch;  3 = bf16 row-major
// ---------------------------------------------------------------------------
template<int EPI>
__global__ __launch_bounds__(256, 4) void gemmk(
    const u16* __restrict__ A, long long aStride,
    const u16* __restrict__ B, long long bStride,
    void* __restrict__ out0, long long cStride,
    int M, int N, int K, int lda, int ldb, int ldc, float scale)
{
    constexpr int ASEC  = 128 * 32;          // u16 per buffer, A section
    constexpr int BUFSZ = ASEC + 128 * 32;   // + B section
    constexpr int NU    = 4;                 // stage units (A:2, B:2)

    __shared__ __align__(16) u16 L[2 * BUFSZ];
    const int tid  = threadIdx.x;
    const int wave = tid >> 6, lane = tid & 63;

    // bijective XCD-aware block swizzle (all launches have nwg % 8 == 0)
    const int gx = gridDim.x, gy = gridDim.y;
    const int nwg = gx * gy * gridDim.z;
    int flat = (blockIdx.z * gy + blockIdx.y) * gx + blockIdx.x;
    flat = (flat & 7) * (nwg >> 3) + (flat >> 3);
    const int bx = flat % gx, by = (flat / gx) % gy, bz = flat / (gx * gy);

    const u16* pA = A + (size_t)bz * aStride;
    const u16* pB = B + (size_t)bz * bStride;
    const int m0 = by * 128, n0 = bx * 128;

    // ---- staging units: each = 2048 u16 (256 thr x 16B), linear LDS dest;
    // 4 slots/row, stored chunk = slot ^ ((row>>1)&3)  (pre-swizzled source)
    const u16* src[NU];
    int dst[NU];
#pragma unroll
    for (int q = 0; q < 2; q++) {
        const int s = q * 256 + tid, row = s >> 2, c = (s & 3) ^ ((row >> 1) & 3);
        src[q]     = pA + (size_t)(m0 + row) * lda + c * 8;
        dst[q]     = q * 2048 + wave * 512;
        src[2 + q] = pB + (size_t)(n0 + row) * ldb + c * 8;
        dst[2 + q] = ASEC + q * 2048 + wave * 512;
    }

    // ---- fragment geometry (16x16 frags; wave = 64x64 quadrant)
    const int fr = lane & 15, ch = lane >> 4;
    const int wr = (wave >> 1) * 64, wc = (wave & 1) * 64;

    const int NT = K >> 5;

    // ---- prologue: stage tile 0 into buffer 0
#pragma unroll
    for (int u = 0; u < NU; u++) { gload_lds16(src[u], &L[dst[u]]); src[u] += 32; }
    __syncthreads();

    f32x4 acc[4][4] = {};
    int cur = 0;

    for (int kt = 0; kt < NT; ++kt) {
        const int cOff = cur * BUFSZ;
        const int sOff = BUFSZ - cOff;
        if (kt + 1 < NT) {
#pragma unroll
            for (int u = 0; u < NU; u++) { gload_lds16(src[u], &L[sOff + dst[u]]); src[u] += 32; }
        }

        bf16x8 ah[4], bh[4];
#pragma unroll
        for (int i = 0; i < 4; i++) {
            const int r = wr + i * 16 + fr;
            ah[i] = *(const bf16x8*)&L[cOff + r * 32 + ((ch ^ ((r >> 1) & 3)) << 3)];
        }
#pragma unroll
        for (int j = 0; j < 4; j++) {
            const int r = wc + j * 16 + fr;
            bh[j] = *(const bf16x8*)&L[cOff + ASEC + r * 32 + ((ch ^ ((r >> 1) & 3)) << 3)];
        }

#pragma unroll
        for (int i = 0; i < 4; i++)
#pragma unroll
            for (int j = 0; j < 4; j++)
                acc[i][j] = MFMA16(ah[i], bh[j], acc[i][j], 0, 0, 0);

        __syncthreads();     // drains vmcnt (staging) + lgkm; swap buffers
        cur ^= 1;
    }

    // ---- epilogue: C/D layout col = lane&15, row = (lane>>4)*4 + r
#pragma unroll
    for (int i = 0; i < 4; i++)
#pragma unroll
        for (int j = 0; j < 4; j++)
#pragma unroll
            for (int r = 0; r < 4; r++) {
                const int row = m0 + wr + i * 16 + (lane >> 4) * 4 + r;
                const int col = n0 + wc + j * 16 + (lane & 15);
                const float v = acc[i][j][r] * scale;
                if constexpr (EPI == 1) {
                    ((float*)out0)[(size_t)bz * cStride + (size_t)row * ldc + col] = v;
                } else if constexpr (EPI == 2) {  // V^T bf16, per-batch
                    const int b = row >> 11, ll = row & 2047;
                    ((u16*)out0)[(size_t)b * (2048 * 1024) + (size_t)col * 2048 + ll] = f2bf(v);
                } else {                          // EPI == 3: bf16 row-major
                    ((u16*)out0)[(size_t)bz * cStride + (size_t)row * ldc + col] = f2bf(v);
                }
            }
}

// ---------------------------------------------------------------------------
__global__ __launch_bounds__(256) void cast_bf16(
    const float* __restrict__ x, u16* __restrict__ o)
{
    const size_t i = ((size_t)blockIdx.x * 256 + threadIdx.x) * 4;
    const float4 v = *(const float4*)&x[i];
    ushort4 h;
    h.x = f2bf(v.x); h.y = f2bf(v.y); h.z = f2bf(v.z); h.w = f2bf(v.w);
    *(ushort4*)&o[i] = h;
}

// ---------------------------------------------------------------------------
__global__ __launch_bounds__(256) void transpose_hi(
    const float* __restrict__ W, u16* __restrict__ thi)
{
    __shared__ float t[64][65];
    const int tid = threadIdx.x;
    const int r0 = blockIdx.y * 64, c0 = blockIdx.x * 64;
#pragma unroll
    for (int it = 0; it < 16; it++) {
        const int idx = it * 256 + tid, rr = idx >> 6, cc = idx & 63;
        t[rr][cc] = W[(size_t)(r0 + rr) * 1024 + (c0 + cc)];
    }
    __syncthreads();
#pragma unroll
    for (int it = 0; it < 16; it++) {
        const int idx = it * 256 + tid, nn = idx >> 6, kk = idx & 63;
        thi[(size_t)(c0 + nn) * 1024 + (r0 + kk)] = f2bf(t[kk][nn]);
    }
}

// ---------------------------------------------------------------------------
// Row softmax over 2048 fp32 scores, written IN PLACE as P bf16 (row head)
// ---------------------------------------------------------------------------
__global__ __launch_bounds__(256) void softmax_rows(float* __restrict__ S)
{
    const int r   = blockIdx.x;                 // 0..8191 (batch*2048 + l)
    float* row    = S + (size_t)r * 2048;
    const int tid = threadIdx.x;

    const float4 a = *(const float4*)&row[tid * 8];
    const float4 b = *(const float4*)&row[tid * 8 + 4];
    float v[8] = {a.x, a.y, a.z, a.w, b.x, b.y, b.z, b.w};

    float m = v[0];
#pragma unroll
    for (int j = 1; j < 8; j++) m = fmaxf(m, v[j]);
    for (int o = 32; o; o >>= 1) m = fmaxf(m, __shfl_xor(m, o));
    __shared__ float redm[4], reds[4];
    if ((tid & 63) == 0) redm[tid >> 6] = m;
    __syncthreads();
    m = fmaxf(fmaxf(redm[0], redm[1]), fmaxf(redm[2], redm[3]));

    float e[8], s = 0.f;
#pragma unroll
    for (int j = 0; j < 8; j++) { e[j] = __expf(v[j] - m); s += e[j]; }
    for (int o = 32; o; o >>= 1) s += __shfl_xor(s, o);
    if ((tid & 63) == 0) reds[tid >> 6] = s;
    __syncthreads();
    s = reds[0] + reds[1] + reds[2] + reds[3];
    const float inv = 1.f / s;

    u16* ph = (u16*)row;          // all reads of this row completed (barriers)
    ushort4 h0, h1;
    h0.x = f2bf(e[0] * inv); h0.y = f2bf(e[1] * inv);
    h0.z = f2bf(e[2] * inv); h0.w = f2bf(e[3] * inv);
    h1.x = f2bf(e[4] * inv); h1.y = f2bf(e[5] * inv);
    h1.z = f2bf(e[6] * inv); h1.w = f2bf(e[7] * inv);
    *(ushort4*)&ph[tid * 8]     = h0;
    *(ushort4*)&ph[tid * 8 + 4] = h1;
}

// ---------------------------------------------------------------------------
__global__ __launch_bounds__(256) void pool_partial(
    const float* __restrict__ H2, const float* __restrict__ wO,
    float* __restrict__ partial)
{
    const int b = blockIdx.x, chunk = blockIdx.y;
    const int tid = threadIdx.x;
    const float* Hb = H2 + (size_t)b * 2048 * 1024 + (size_t)chunk * 64 * 1024;
    const float4 w = *(const float4*)&wO[tid * 4];
    float acc = 0.f;
#pragma unroll 4
    for (int l = 0; l < 64; l++) {
        const float4 h = *(const float4*)&Hb[(size_t)l * 1024 + tid * 4];
        acc += h.x * w.x + h.y * w.y + h.z * w.z + h.w * w.w;
    }
    for (int o = 32; o; o >>= 1) acc += __shfl_xor(acc, o);
    __shared__ float red[4];
    if ((tid & 63) == 0) red[tid >> 6] = acc;
    __syncthreads();
    if (tid == 0) partial[b * 32 + chunk] = red[0] + red[1] + red[2] + red[3];
}

__global__ void head_final(const float* __restrict__ partial,
                           const float* __restrict__ bO, float* __restrict__ out)
{
    const int b = threadIdx.x;                  // 0..3
    if (b >= 4) return;
    float s = 0.f;
#pragma unroll
    for (int c = 0; c < 32; c++) s += partial[b * 32 + c];
    const float logit = s * (1.f / 2048.f) + bO[0];
    out[b] = 1.f / (1.f + __expf(-logit));
}

// ---------------------------------------------------------------------------
extern "C" void kernel_launch(void* const* d_in, const int* in_sizes, int n_in,
                              void* d_out, int out_size, void* d_ws, size_t ws_size,
                              hipStream_t stream)
{
    const float* X   = (const float*)d_in[0];
    const float* Wq1 = (const float*)d_in[1];
    const float* Wk1 = (const float*)d_in[2];
    const float* Wv1 = (const float*)d_in[3];
    const float* Wq2 = (const float*)d_in[4];
    const float* Wk2 = (const float*)d_in[5];
    const float* Wv2 = (const float*)d_in[6];
    const float* WO  = (const float*)d_in[7];
    const float* bO  = (const float*)d_in[8];
    float* out = (float*)d_out;

    uint8_t* ws = (uint8_t*)d_ws;
    const size_t MB = 1ull << 20;
    u16* Xb   = (u16*)(ws + 0);          // X bf16; later H1 bf16
    u16* Qb   = (u16*)(ws + 32 * MB);    // Q bf16
    u16* Kb   = (u16*)(ws + 64 * MB);    // K bf16
    u16* Vtb  = (u16*)(ws + 96 * MB);    // V^T bf16 per-batch
    u16* Wt   = (u16*)(ws + 128 * MB);   // 6x W^T bf16 (1M u16 each)
    float* S  = (float*)(ws + 152 * MB); // 64 MB scores / P
    float* H2 = (float*)(ws + 32 * MB);  // fp32, overwrites Qb (dead by then)
    float* partial = (float*)(ws + 80 * MB);

    auto Wh = [&](int i) { return Wt + (size_t)i * 1048576; };
    const float* Wsrc[6] = {Wq1, Wk1, Wv1, Wq2, Wk2, Wv2};

    // ---- prep: cast X to bf16, transpose weights to bf16
    cast_bf16<<<8192, 256, 0, stream>>>(X, Xb);   // 8M elems
    for (int i = 0; i < 6; i++)
        transpose_hi<<<dim3(16, 16), 256, 0, stream>>>(Wsrc[i], Wh(i));

    const long long LD2 = 2048LL * 1024;   // 2M: Q/K/V & H batch stride
    const long long SST = 2048LL * 2048;   // 4M: S batch stride (floats)
    const long long PST = 2048LL * 4096;   // 8M: P batch stride (u16)

    for (int blk = 0; blk < 2; blk++) {
        const int w0 = blk * 3;
        // Q/K/V projections: grid (8, 64) = 512 blocks each
        gemmk<3><<<dim3(8, 64, 1), 256, 0, stream>>>(
            Xb, 0, Wh(w0 + 0), 0, Qb, 0,
            8192, 1024, 1024, 1024, 1024, 1024, 1.f);
        gemmk<3><<<dim3(8, 64, 1), 256, 0, stream>>>(
            Xb, 0, Wh(w0 + 1), 0, Kb, 0,
            8192, 1024, 1024, 1024, 1024, 1024, 1.f);
        gemmk<2><<<dim3(8, 64, 1), 256, 0, stream>>>(
            Xb, 0, Wh(w0 + 2), 0, Vtb, 0,
            8192, 1024, 1024, 1024, 1024, 1024, 1.f);
        // S = Q.K^T / sqrt(D): grid (16, 16, 4) = 1024 blocks
        gemmk<1><<<dim3(16, 16, 4), 256, 0, stream>>>(
            Qb, LD2, Kb, LD2, S, SST,
            2048, 2048, 1024, 1024, 1024, 2048, 0.03125f);
        // softmax rows, in-place -> P bf16
        softmax_rows<<<8192, 256, 0, stream>>>(S);
        // O = P.V: grid (8, 16, 4) = 512 blocks
        if (blk == 0) {
            gemmk<3><<<dim3(8, 16, 4), 256, 0, stream>>>(
                (u16*)S, PST, Vtb, LD2, Xb, LD2,
                2048, 1024, 2048, 4096, 2048, 1024, 1.f);   // H1 bf16 -> Xb region
        } else {
            gemmk<1><<<dim3(8, 16, 4), 256, 0, stream>>>(
                (u16*)S, PST, Vtb, LD2, H2, LD2,
                2048, 1024, 2048, 4096, 2048, 1024, 1.f);   // H2 fp32
        }
    }

    pool_partial<<<dim3(4, 32), 256, 0, stream>>>(H2, WO, partial);
    head_final<<<1, 64, 0, stream>>>(partial, bO, out);
}